// Round 2
// baseline (5374.186 us; speedup 1.0000x reference)
//
#include <hip/hip_runtime.h>
#include <hip/hip_bf16.h>

#define B_ 64
#define L_ 1024
#define D_ 256
#define M_ (B_*L_)

__device__ __forceinline__ float sigmoidf_(float z) { return 1.0f/(1.0f + __expf(-z)); }

// ---------------- K1: qe = Eq[question] ----------------
__global__ void k_embed(const int* __restrict__ qs, const float* __restrict__ Eq,
                        float* __restrict__ qe) {
  int idx4 = blockIdx.x*256 + threadIdx.x;   // one float4 per thread
  int row = idx4 >> 6;                        // 64 float4 per row of D=256
  int c4  = idx4 & 63;
  int q = qs[row];
  ((float4*)qe)[idx4] = ((const float4*)Eq)[q*64 + c4];
}

// ---------------- K2: fused causal attention ----------------
// Per block: TI=32 rows of one batch. Streams j-tiles of TJ=16.
// Outputs: attq = Wnorm @ qe, stv = sum(W), s1v = sum(W*c).
// Exact reference algebra: W_j = e_j / (Zs + 1e-8*(Zs+Zdiag)), no max needed
// (scores ~ +/-0.05 so exp is safe).
#define TI 32
#define TJ 16
#define QSTR 260   // pad 256->260: conflict-free strided access, keeps 16B align

__global__ __launch_bounds__(256) void k_attn(const float* __restrict__ qe,
                       const int* __restrict__ cs,
                       float* __restrict__ attq, float* __restrict__ stv,
                       float* __restrict__ s1v) {
  __shared__ float sQi[TI*QSTR];
  __shared__ float sQj[TJ*QSTR];
  __shared__ float sc[TI*17];
  __shared__ float scj[TJ];
  int t = threadIdx.x;
  int b = blockIdx.x >> 5;            // 32 row-tiles per batch
  int i0 = (blockIdx.x & 31) * TI;
  int r = t >> 3, g = t & 7;          // 32 rows x 8 threads/row
  int i = i0 + r;
  // load Qi tile (32 rows x 256)
  {
    int lr = t >> 3, lc = (t & 7) * 32;
    const float* src = qe + (b*L_ + i0 + lr)*D_ + lc;
    float* dst = sQi + lr*QSTR + lc;
    #pragma unroll
    for (int m = 0; m < 8; ++m) ((float4*)dst)[m] = ((const float4*)src)[m];
  }
  float acc[32];
  #pragma unroll
  for (int k = 0; k < 32; ++k) acc[k] = 0.f;
  float Zs = 0.f, Zd = 0.f, S1 = 0.f;
  int njt = (i0 >> 4) + 2;            // j-tiles cover j in [0, i0+32)
  for (int jt = 0; jt < njt; ++jt) {
    int j0 = jt * TJ;
    __syncthreads();
    {  // load Qj tile (16 rows x 256)
      int lr = t >> 4, lc = (t & 15) * 16;
      const float* src = qe + (b*L_ + j0 + lr)*D_ + lc;
      float* dst = sQj + lr*QSTR + lc;
      #pragma unroll
      for (int m = 0; m < 4; ++m) ((float4*)dst)[m] = ((const float4*)src)[m];
    }
    if (t < TJ) scj[t] = (float)cs[b*L_ + j0 + t];
    __syncthreads();
    // score phase: each thread does jj = 2g, 2g+1
    {
      float s0 = 0.f, s1_ = 0.f;
      const float* qi  = sQi + r*QSTR;
      const float* qj0 = sQj + (2*g)*QSTR;
      const float* qj1 = qj0 + QSTR;
      for (int d = 0; d < D_; ++d) {
        float qv = qi[d];
        s0  = fmaf(qv, qj0[d], s0);
        s1_ = fmaf(qv, qj1[d], s1_);
      }
      sc[r*17 + 2*g]     = __expf(s0);
      sc[r*17 + 2*g + 1] = __expf(s1_);
    }
    __syncthreads();
    // accumulate phase: thread owns d = 32k + 4g + {0..3}
    for (int jj = 0; jj < TJ; ++jj) {
      int j = j0 + jj;
      float e = sc[r*17 + jj];
      if (j < i) {
        Zs += e;
        S1 = fmaf(e, scj[jj], S1);
        const float4* qjp = (const float4*)(sQj + jj*QSTR + 4*g);
        #pragma unroll
        for (int k = 0; k < 8; ++k) {
          float4 v = qjp[8*k];
          acc[4*k+0] = fmaf(e, v.x, acc[4*k+0]);
          acc[4*k+1] = fmaf(e, v.y, acc[4*k+1]);
          acc[4*k+2] = fmaf(e, v.z, acc[4*k+2]);
          acc[4*k+3] = fmaf(e, v.w, acc[4*k+3]);
        }
      } else if (j == i) {
        Zd = e;
      }
    }
  }
  float denom = Zs + 1e-8f*(Zs + Zd);
  float inv = 1.0f / denom;           // row 0: acc=0 so attq=0 exactly
  int row = b*L_ + i;
  float4* outp = (float4*)(attq + row*D_ + 4*g);
  #pragma unroll
  for (int k = 0; k < 8; ++k) {
    float4 v;
    v.x = acc[4*k+0]*inv; v.y = acc[4*k+1]*inv;
    v.z = acc[4*k+2]*inv; v.w = acc[4*k+3]*inv;
    outp[8*k] = v;
  }
  if (g == 0) { stv[row] = Zs*inv; s1v[row] = S1*inv; }
}

// ---------------- K3: fused double GEMM  Q = (H@W1^T+b1)*sig(H@W2^T+b2) ----
// H constructed on the fly in the A-load: [qe | Ec[c] | attq | s1*Ec1+(st-s1)*Ec0 | cqc]
// BM=64, BN=64, BK=16; 256 threads, 4x4 micro-tile, 2 accumulator sets.
__global__ __launch_bounds__(256) void k_mlp(const float* __restrict__ qe,
    const float* __restrict__ attq, const float* __restrict__ stv,
    const float* __restrict__ s1v, const int* __restrict__ cs,
    const float* __restrict__ cqc, const float* __restrict__ Ec,
    const float* __restrict__ W1w, const float* __restrict__ W1b,
    const float* __restrict__ W2w, const float* __restrict__ W2b,
    float* __restrict__ out) {
  __shared__ float sA [16*64];
  __shared__ float sB1[16*64];
  __shared__ float sB2[16*64];
  int t = threadIdx.x;
  int rowB = blockIdx.x * 64;
  int n0 = blockIdx.y * 64;
  int tr = t >> 4, tc = t & 15;
  int lrow = t >> 2, lk4 = (t & 3) * 4;
  int arow = rowB + lrow;
  float acc1[16], acc2[16];
  #pragma unroll
  for (int k = 0; k < 16; ++k) { acc1[k] = 0.f; acc2[k] = 0.f; }
  for (int k0 = 0; k0 < 1280; k0 += 16) {
    __syncthreads();
    float4 av;
    if (k0 < 256) {
      av = *(const float4*)(qe + arow*D_ + k0 + lk4);
    } else if (k0 < 512) {
      int c = cs[arow];
      av = *(const float4*)(Ec + c*D_ + (k0-256) + lk4);
    } else if (k0 < 768) {
      av = *(const float4*)(attq + arow*D_ + (k0-512) + lk4);
    } else if (k0 < 1024) {
      float s1r = s1v[arow];
      float s0r = stv[arow] - s1r;
      int kk = (k0 - 768) + lk4;
      float4 e1 = *(const float4*)(Ec + D_ + kk);
      float4 e0 = *(const float4*)(Ec + kk);
      av.x = s1r*e1.x + s0r*e0.x;
      av.y = s1r*e1.y + s0r*e0.y;
      av.z = s1r*e1.z + s0r*e0.z;
      av.w = s1r*e1.w + s0r*e0.w;
    } else {
      av = *(const float4*)(cqc + arow*D_ + (k0-1024) + lk4);
    }
    sA[(lk4+0)*64 + lrow] = av.x;
    sA[(lk4+1)*64 + lrow] = av.y;
    sA[(lk4+2)*64 + lrow] = av.z;
    sA[(lk4+3)*64 + lrow] = av.w;
    float4 b1v = *(const float4*)(W1w + (n0+lrow)*1280 + k0 + lk4);
    float4 b2v = *(const float4*)(W2w + (n0+lrow)*1280 + k0 + lk4);
    sB1[(lk4+0)*64 + lrow] = b1v.x;
    sB1[(lk4+1)*64 + lrow] = b1v.y;
    sB1[(lk4+2)*64 + lrow] = b1v.z;
    sB1[(lk4+3)*64 + lrow] = b1v.w;
    sB2[(lk4+0)*64 + lrow] = b2v.x;
    sB2[(lk4+1)*64 + lrow] = b2v.y;
    sB2[(lk4+2)*64 + lrow] = b2v.z;
    sB2[(lk4+3)*64 + lrow] = b2v.w;
    __syncthreads();
    #pragma unroll
    for (int kk = 0; kk < 16; ++kk) {
      float4 a  = *(const float4*)(sA  + kk*64 + tr*4);
      float4 b1 = *(const float4*)(sB1 + kk*64 + tc*4);
      float4 b2 = *(const float4*)(sB2 + kk*64 + tc*4);
      float aa[4]  = {a.x, a.y, a.z, a.w};
      float bb1[4] = {b1.x, b1.y, b1.z, b1.w};
      float bb2[4] = {b2.x, b2.y, b2.z, b2.w};
      #pragma unroll
      for (int ii = 0; ii < 4; ++ii)
        #pragma unroll
        for (int jj = 0; jj < 4; ++jj) {
          acc1[ii*4+jj] = fmaf(aa[ii], bb1[jj], acc1[ii*4+jj]);
          acc2[ii*4+jj] = fmaf(aa[ii], bb2[jj], acc2[ii*4+jj]);
        }
    }
  }
  #pragma unroll
  for (int ii = 0; ii < 4; ++ii) {
    int row = rowB + tr*4 + ii;
    float oo[4];
    #pragma unroll
    for (int jj = 0; jj < 4; ++jj) {
      int n = n0 + tc*4 + jj;
      float z1 = acc1[ii*4+jj] + W1b[n];
      float z2 = acc2[ii*4+jj] + W2b[n];
      oo[jj] = z1 * sigmoidf_(z2);
    }
    float4 o; o.x = oo[0]; o.y = oo[1]; o.z = oo[2]; o.w = oo[3];
    *(float4*)(out + row*D_ + n0 + tc*4) = o;
  }
}

// ---------------- K4: causal conv K=4, GLU, residual (one layer) ----------
// im2col GEMM M=65536, N=64 a-cols (+ paired b-cols), K=1024. Same tiling as k_mlp.
__global__ __launch_bounds__(256) void k_conv(const float* __restrict__ xin,
    const float* __restrict__ w, const float* __restrict__ bias,
    float* __restrict__ xout) {
  __shared__ float sA [16*64];
  __shared__ float sBa[16*64];
  __shared__ float sBb[16*64];
  int t = threadIdx.x;
  int rowB = blockIdx.x * 64;
  int n0 = blockIdx.y * 64;
  int tr = t >> 4, tc = t & 15;
  int lrow = t >> 2, lk4 = (t & 3) * 4;
  int arow = rowB + lrow;
  int al = arow & (L_-1);
  int lkk = t >> 4, ln4 = (t & 15) * 4;
  float acca[16], accb[16];
  #pragma unroll
  for (int k = 0; k < 16; ++k) { acca[k] = 0.f; accb[k] = 0.f; }
  for (int k0 = 0; k0 < 1024; k0 += 16) {
    int tk = k0 >> 8;        // conv tap 0..3 (block-uniform)
    int ic0 = k0 & 255;
    __syncthreads();
    float4 av = make_float4(0.f, 0.f, 0.f, 0.f);
    if (al + tk >= 3)        // causal left pad within batch
      av = *(const float4*)(xin + (arow + tk - 3)*D_ + ic0 + lk4);
    sA[(lk4+0)*64 + lrow] = av.x;
    sA[(lk4+1)*64 + lrow] = av.y;
    sA[(lk4+2)*64 + lrow] = av.z;
    sA[(lk4+3)*64 + lrow] = av.w;
    float4 ba = *(const float4*)(w + (k0+lkk)*512 + n0 + ln4);
    float4 bb = *(const float4*)(w + (k0+lkk)*512 + n0 + 256 + ln4);
    *(float4*)(sBa + lkk*64 + ln4) = ba;
    *(float4*)(sBb + lkk*64 + ln4) = bb;
    __syncthreads();
    #pragma unroll
    for (int kk = 0; kk < 16; ++kk) {
      float4 a  = *(const float4*)(sA  + kk*64 + tr*4);
      float4 b1 = *(const float4*)(sBa + kk*64 + tc*4);
      float4 b2 = *(const float4*)(sBb + kk*64 + tc*4);
      float aa[4]  = {a.x, a.y, a.z, a.w};
      float bb1[4] = {b1.x, b1.y, b1.z, b1.w};
      float bb2[4] = {b2.x, b2.y, b2.z, b2.w};
      #pragma unroll
      for (int ii = 0; ii < 4; ++ii)
        #pragma unroll
        for (int jj = 0; jj < 4; ++jj) {
          acca[ii*4+jj] = fmaf(aa[ii], bb1[jj], acca[ii*4+jj]);
          accb[ii*4+jj] = fmaf(aa[ii], bb2[jj], accb[ii*4+jj]);
        }
    }
  }
  #pragma unroll
  for (int ii = 0; ii < 4; ++ii) {
    int row = rowB + tr*4 + ii;
    float4 rv = *(const float4*)(xin + row*D_ + n0 + tc*4);
    float rr[4] = {rv.x, rv.y, rv.z, rv.w};
    float oo[4];
    #pragma unroll
    for (int jj = 0; jj < 4; ++jj) {
      int n = n0 + tc*4 + jj;
      float za = acca[ii*4+jj] + bias[n];
      float zb = accb[ii*4+jj] + bias[n + 256];
      oo[jj] = za * sigmoidf_(zb) + rr[jj];
    }
    float4 o; o.x = oo[0]; o.y = oo[1]; o.z = oo[2]; o.w = oo[3];
    *(float4*)(xout + row*D_ + n0 + tc*4) = o;
  }
}

// ---------------- K5: predict = sigmoid(sum_d x[:, :-1]*qe[:, 1:]) ----------
// qe re-gathered from Eq (qe buffer was recycled to save workspace).
__global__ void k_pred(const float* __restrict__ x, const int* __restrict__ qs,
                       const float* __restrict__ Eq, float* __restrict__ out) {
  int lane = threadIdx.x & 63;
  int wv = threadIdx.x >> 6;
  int oi = blockIdx.x*4 + wv;      // 0..65471
  int b = oi / 1023;
  int tp = oi - b*1023;
  int row = b*L_ + tp;
  int q = qs[row + 1];
  float4 a = ((const float4*)(x  + row*D_))[lane];
  float4 qv = ((const float4*)(Eq + q*D_))[lane];
  float s = a.x*qv.x + a.y*qv.y + a.z*qv.z + a.w*qv.w;
  #pragma unroll
  for (int off = 32; off; off >>= 1) s += __shfl_xor(s, off);
  if (lane == 0) out[oi] = sigmoidf_(s);
}

extern "C" void kernel_launch(void* const* d_in, const int* in_sizes, int n_in,
                              void* d_out, int out_size, void* d_ws, size_t ws_size,
                              hipStream_t stream) {
  const int*   qs  = (const int*)d_in[0];
  const int*   cs  = (const int*)d_in[1];
  const float* cqc = (const float*)d_in[2];
  const float* Eq  = (const float*)d_in[3];
  const float* Ec  = (const float*)d_in[4];
  const float* W1w = (const float*)d_in[5];
  const float* W1b = (const float*)d_in[6];
  const float* W2w = (const float*)d_in[7];
  const float* W2b = (const float*)d_in[8];
  const float* cw  = (const float*)d_in[9];
  const float* cb  = (const float*)d_in[10];
  float* out = (float*)d_out;

  // workspace: 3 x [M,D] buffers + 2 x [M] vectors = 192.5 MiB total.
  // buf1 holds qe until k_mlp is done, then recycled as a conv ping-pong buf.
  float* ws   = (float*)d_ws;
  float* buf1 = ws;                           // qe, later conv out #1
  float* buf2 = buf1 + (size_t)M_*D_;         // attq, later conv out #2
  float* buf3 = buf2 + (size_t)M_*D_;         // mlp out, later conv out #3
  float* stv  = buf3 + (size_t)M_*D_;
  float* s1v  = stv  + M_;

  k_embed<<<(M_*D_/4)/256, 256, 0, stream>>>(qs, Eq, buf1);
  k_attn <<<B_*(L_/TI), 256, 0, stream>>>(buf1, cs, buf2, stv, s1v);
  k_mlp  <<<dim3(M_/64, 4), 256, 0, stream>>>(buf1, buf2, stv, s1v, cs, cqc, Ec,
                                              W1w, W1b, W2w, W2b, buf3);
  // conv ping-pong: buf3 -> buf1 -> buf2 -> buf3
  k_conv <<<dim3(M_/64, 4), 256, 0, stream>>>(buf3, cw,           cb,        buf1);
  k_conv <<<dim3(M_/64, 4), 256, 0, stream>>>(buf1, cw + 524288,  cb + 512,  buf2);
  k_conv <<<dim3(M_/64, 4), 256, 0, stream>>>(buf2, cw + 1048576, cb + 1024, buf3);
  k_pred <<<(B_*(L_-1))/4, 256, 0, stream>>>(buf3, qs, Eq, out);
}

// Round 3
// 2004.583 us; speedup vs baseline: 2.6809x; 2.6809x over previous
//
#include <hip/hip_runtime.h>
#include <hip/hip_bf16.h>

#define B_ 64
#define L_ 1024
#define D_ 256
#define M_ (B_*L_)

typedef __attribute__((ext_vector_type(8))) short s16x8;
typedef __attribute__((ext_vector_type(4))) float f32x4;

__device__ __forceinline__ float sigmoidf_(float z) { return 1.0f/(1.0f + __expf(-z)); }

__device__ __forceinline__ unsigned short f2bf(float x) {
  unsigned int u = __builtin_bit_cast(unsigned int, x);
  u += 0x7fffu + ((u >> 16) & 1u);          // RNE
  return (unsigned short)(u >> 16);
}
__device__ __forceinline__ float bf2f(unsigned short u) {
  unsigned int x = ((unsigned int)u) << 16;
  return __builtin_bit_cast(float, x);
}
__device__ __forceinline__ uint4 pack8(const float* f) {
  union { unsigned short u[8]; uint4 v; } r;
  #pragma unroll
  for (int i = 0; i < 8; ++i) r.u[i] = f2bf(f[i]);
  return r.v;
}

// ---------------- K1: qe = Eq[question] (fp32, feeds attn + mlp staging) ----
__global__ void k_embed(const int* __restrict__ qs, const float* __restrict__ Eq,
                        float* __restrict__ qe) {
  int idx4 = blockIdx.x*256 + threadIdx.x;
  int row = idx4 >> 6;
  int c4  = idx4 & 63;
  int q = qs[row];
  ((float4*)qe)[idx4] = ((const float4*)Eq)[q*64 + c4];
}

// ---------------- K2: fused causal attention (unchanged from R2) ----------
#define TI 32
#define TJ 16
#define QSTR 260

__global__ __launch_bounds__(256) void k_attn(const float* __restrict__ qe,
                       const int* __restrict__ cs,
                       float* __restrict__ attq, float* __restrict__ stv,
                       float* __restrict__ s1v) {
  __shared__ float sQi[TI*QSTR];
  __shared__ float sQj[TJ*QSTR];
  __shared__ float sc[TI*17];
  __shared__ float scj[TJ];
  int t = threadIdx.x;
  int b = blockIdx.x >> 5;
  int i0 = (blockIdx.x & 31) * TI;
  int r = t >> 3, g = t & 7;
  int i = i0 + r;
  {
    int lr = t >> 3, lc = (t & 7) * 32;
    const float* src = qe + (b*L_ + i0 + lr)*D_ + lc;
    float* dst = sQi + lr*QSTR + lc;
    #pragma unroll
    for (int m = 0; m < 8; ++m) ((float4*)dst)[m] = ((const float4*)src)[m];
  }
  float acc[32];
  #pragma unroll
  for (int k = 0; k < 32; ++k) acc[k] = 0.f;
  float Zs = 0.f, Zd = 0.f, S1 = 0.f;
  int njt = (i0 >> 4) + 2;
  for (int jt = 0; jt < njt; ++jt) {
    int j0 = jt * TJ;
    __syncthreads();
    {
      int lr = t >> 4, lc = (t & 15) * 16;
      const float* src = qe + (b*L_ + j0 + lr)*D_ + lc;
      float* dst = sQj + lr*QSTR + lc;
      #pragma unroll
      for (int m = 0; m < 4; ++m) ((float4*)dst)[m] = ((const float4*)src)[m];
    }
    if (t < TJ) scj[t] = (float)cs[b*L_ + j0 + t];
    __syncthreads();
    {
      float s0 = 0.f, s1_ = 0.f;
      const float* qi  = sQi + r*QSTR;
      const float* qj0 = sQj + (2*g)*QSTR;
      const float* qj1 = qj0 + QSTR;
      for (int d = 0; d < D_; ++d) {
        float qv = qi[d];
        s0  = fmaf(qv, qj0[d], s0);
        s1_ = fmaf(qv, qj1[d], s1_);
      }
      sc[r*17 + 2*g]     = __expf(s0);
      sc[r*17 + 2*g + 1] = __expf(s1_);
    }
    __syncthreads();
    for (int jj = 0; jj < TJ; ++jj) {
      int j = j0 + jj;
      float e = sc[r*17 + jj];
      if (j < i) {
        Zs += e;
        S1 = fmaf(e, scj[jj], S1);
        const float4* qjp = (const float4*)(sQj + jj*QSTR + 4*g);
        #pragma unroll
        for (int k = 0; k < 8; ++k) {
          float4 v = qjp[8*k];
          acc[4*k+0] = fmaf(e, v.x, acc[4*k+0]);
          acc[4*k+1] = fmaf(e, v.y, acc[4*k+1]);
          acc[4*k+2] = fmaf(e, v.z, acc[4*k+2]);
          acc[4*k+3] = fmaf(e, v.w, acc[4*k+3]);
        }
      } else if (j == i) {
        Zd = e;
      }
    }
  }
  float denom = Zs + 1e-8f*(Zs + Zd);
  float inv = 1.0f / denom;
  int row = b*L_ + i;
  float4* outp = (float4*)(attq + row*D_ + 4*g);
  #pragma unroll
  for (int k = 0; k < 8; ++k) {
    float4 v;
    v.x = acc[4*k+0]*inv; v.y = acc[4*k+1]*inv;
    v.z = acc[4*k+2]*inv; v.w = acc[4*k+3]*inv;
    outp[8*k] = v;
  }
  if (g == 0) { stv[row] = Zs*inv; s1v[row] = S1*inv; }
}

// ---------------- weight conversion: fp32 -> bf16 (elementwise) ------------
__global__ void k_cvt(const float* __restrict__ src, unsigned short* __restrict__ dst) {
  int i = blockIdx.x*256 + threadIdx.x;
  float4 v = ((const float4*)src)[i];
  union { unsigned short u[4]; uint2 q; } o;
  o.u[0] = f2bf(v.x); o.u[1] = f2bf(v.y); o.u[2] = f2bf(v.z); o.u[3] = f2bf(v.w);
  ((uint2*)dst)[i] = o.q;
}

// ------- conv weight transpose+convert: w[l][tap][ic][oc] -> wT[l][oc][tap*256+ic]
__global__ __launch_bounds__(256) void k_cvt_convw(const float* __restrict__ w,
                                                   unsigned short* __restrict__ wT) {
  __shared__ unsigned short lds[64*72];
  int l = blockIdx.z;
  int k0 = blockIdx.x * 64;
  int oc0 = blockIdx.y * 64;
  const float* src = w + (size_t)l*524288;
  unsigned short* dst = wT + (size_t)l*524288;
  int t = threadIdx.x;
  #pragma unroll
  for (int it = 0; it < 4; ++it) {
    int kr = it*16 + (t >> 4);
    int oc = (t & 15)*4;
    float4 v = *(const float4*)(src + (size_t)(k0+kr)*512 + oc0 + oc);
    lds[(oc+0)*72 + kr] = f2bf(v.x);
    lds[(oc+1)*72 + kr] = f2bf(v.y);
    lds[(oc+2)*72 + kr] = f2bf(v.z);
    lds[(oc+3)*72 + kr] = f2bf(v.w);
  }
  __syncthreads();
  #pragma unroll
  for (int it = 0; it < 2; ++it) {
    int ocr = it*32 + (t >> 3);
    int kx = (t & 7)*8;
    *(uint4*)(dst + (size_t)(oc0+ocr)*1024 + k0 + kx) = *(const uint4*)&lds[ocr*72 + kx];
  }
}

// ---------------- K3: MFMA fused double GEMM (MLP + GLU) -------------------
// 128x128 tile, BK=32, 4 waves x 64x64 quadrant, 16x16x32 bf16 MFMA.
// A = H on the fly: [qe | Ec[c] | attq | s1*Ec1+(st-s1)*Ec0 | cqc] -> bf16.
#define SSTR 40   // LDS row stride in shorts (80 B): frag reads 2-way max on banks

__global__ __launch_bounds__(256, 2) void k_mlp_mfma(
    const float* __restrict__ qe, const float* __restrict__ attq,
    const float* __restrict__ stv, const float* __restrict__ s1v,
    const int* __restrict__ cs, const float* __restrict__ cqc,
    const float* __restrict__ Ec,
    const unsigned short* __restrict__ W1bf, const float* __restrict__ W1b,
    const unsigned short* __restrict__ W2bf, const float* __restrict__ W2b,
    unsigned short* __restrict__ out) {
  __shared__ unsigned short sA[128*SSTR], sB1[128*SSTR], sB2[128*SSTR];
  int t = threadIdx.x;
  int m0 = blockIdx.x * 128;
  int n0 = blockIdx.y * 128;
  int lr = t >> 1, kh = (t & 1) * 16;
  int arow = m0 + lr;
  int lane = t & 63, wv = t >> 6;
  int moff = (wv & 1) * 64, noff = (wv >> 1) * 64;
  int l15 = lane & 15, koff = (lane >> 4) * 8;
  f32x4 acc1[4][4], acc2[4][4];
  f32x4 zz = {0.f, 0.f, 0.f, 0.f};
  #pragma unroll
  for (int i = 0; i < 4; ++i)
    #pragma unroll
    for (int j = 0; j < 4; ++j) { acc1[i][j] = zz; acc2[i][j] = zz; }
  for (int k0 = 0; k0 < 1280; k0 += 32) {
    __syncthreads();
    {  // A stage: 16 floats/thread -> bf16
      int seg = k0 >> 8;
      int ks = (k0 & 255) + kh;
      float f[16];
      if (seg == 0) {
        const float4* p = (const float4*)(qe + (size_t)arow*D_ + ks);
        #pragma unroll
        for (int m = 0; m < 4; ++m) { float4 v = p[m];
          f[4*m]=v.x; f[4*m+1]=v.y; f[4*m+2]=v.z; f[4*m+3]=v.w; }
      } else if (seg == 1) {
        int c = cs[arow];
        const float4* p = (const float4*)(Ec + (size_t)c*D_ + ks);
        #pragma unroll
        for (int m = 0; m < 4; ++m) { float4 v = p[m];
          f[4*m]=v.x; f[4*m+1]=v.y; f[4*m+2]=v.z; f[4*m+3]=v.w; }
      } else if (seg == 2) {
        const float4* p = (const float4*)(attq + (size_t)arow*D_ + ks);
        #pragma unroll
        for (int m = 0; m < 4; ++m) { float4 v = p[m];
          f[4*m]=v.x; f[4*m+1]=v.y; f[4*m+2]=v.z; f[4*m+3]=v.w; }
      } else if (seg == 3) {
        float s1r = s1v[arow], s0r = stv[arow] - s1r;
        const float4* p1 = (const float4*)(Ec + D_ + ks);
        const float4* p0 = (const float4*)(Ec + ks);
        #pragma unroll
        for (int m = 0; m < 4; ++m) {
          float4 v1 = p1[m], v0 = p0[m];
          f[4*m]   = s1r*v1.x + s0r*v0.x;
          f[4*m+1] = s1r*v1.y + s0r*v0.y;
          f[4*m+2] = s1r*v1.z + s0r*v0.z;
          f[4*m+3] = s1r*v1.w + s0r*v0.w;
        }
      } else {
        const float4* p = (const float4*)(cqc + (size_t)arow*D_ + ks);
        #pragma unroll
        for (int m = 0; m < 4; ++m) { float4 v = p[m];
          f[4*m]=v.x; f[4*m+1]=v.y; f[4*m+2]=v.z; f[4*m+3]=v.w; }
      }
      *(uint4*)&sA[lr*SSTR + kh]     = pack8(f);
      *(uint4*)&sA[lr*SSTR + kh + 8] = pack8(f + 8);
    }
    {  // B stage: already bf16, [n][k] layout
      const uint4* p1 = (const uint4*)(W1bf + (size_t)(n0+lr)*1280 + k0 + kh);
      const uint4* p2 = (const uint4*)(W2bf + (size_t)(n0+lr)*1280 + k0 + kh);
      *(uint4*)&sB1[lr*SSTR + kh]     = p1[0];
      *(uint4*)&sB1[lr*SSTR + kh + 8] = p1[1];
      *(uint4*)&sB2[lr*SSTR + kh]     = p2[0];
      *(uint4*)&sB2[lr*SSTR + kh + 8] = p2[1];
    }
    __syncthreads();
    s16x8 am[4], b1f[4], b2f[4];
    #pragma unroll
    for (int i = 0; i < 4; ++i)
      am[i] = *(const s16x8*)&sA[(moff + i*16 + l15)*SSTR + koff];
    #pragma unroll
    for (int j = 0; j < 4; ++j) {
      b1f[j] = *(const s16x8*)&sB1[(noff + j*16 + l15)*SSTR + koff];
      b2f[j] = *(const s16x8*)&sB2[(noff + j*16 + l15)*SSTR + koff];
    }
    #pragma unroll
    for (int i = 0; i < 4; ++i)
      #pragma unroll
      for (int j = 0; j < 4; ++j) {
        acc1[i][j] = __builtin_amdgcn_mfma_f32_16x16x32_bf16(am[i], b1f[j], acc1[i][j], 0, 0, 0);
        acc2[i][j] = __builtin_amdgcn_mfma_f32_16x16x32_bf16(am[i], b2f[j], acc2[i][j], 0, 0, 0);
      }
  }
  // epilogue: C/D layout col=lane&15, row=(lane>>4)*4+reg [m89]
  #pragma unroll
  for (int j = 0; j < 4; ++j) {
    int col = n0 + noff + j*16 + l15;
    float b1 = W1b[col], b2 = W2b[col];
    #pragma unroll
    for (int i = 0; i < 4; ++i) {
      int rbase = m0 + moff + i*16 + (lane >> 4)*4;
      #pragma unroll
      for (int r = 0; r < 4; ++r) {
        float z1 = acc1[i][j][r] + b1;
        float z2 = acc2[i][j][r] + b2;
        out[(size_t)(rbase + r)*D_ + col] = f2bf(z1 * sigmoidf_(z2));
      }
    }
  }
}

// ---------------- K4: MFMA causal conv K=4 + GLU + residual ----------------
// Same tile structure; A[row][tap*256+ic] = xin_bf16[row+tap-3][ic] (0 left-pad),
// B = wT[oc][k]; a-half oc in [0,256), b-half [256,512), paired per block.
__global__ __launch_bounds__(256, 2) void k_conv_mfma(
    const unsigned short* __restrict__ xin, const unsigned short* __restrict__ wT,
    const float* __restrict__ bias, unsigned short* __restrict__ xout) {
  __shared__ unsigned short sA[128*SSTR], sBa[128*SSTR], sBb[128*SSTR];
  int t = threadIdx.x;
  int m0 = blockIdx.x * 128;
  int n0 = blockIdx.y * 128;
  int lr = t >> 1, kh = (t & 1) * 16;
  int arow = m0 + lr;
  int al = arow & (L_ - 1);
  int lane = t & 63, wv = t >> 6;
  int moff = (wv & 1) * 64, noff = (wv >> 1) * 64;
  int l15 = lane & 15, koff = (lane >> 4) * 8;
  f32x4 acca[4][4], accb[4][4];
  f32x4 zz = {0.f, 0.f, 0.f, 0.f};
  #pragma unroll
  for (int i = 0; i < 4; ++i)
    #pragma unroll
    for (int j = 0; j < 4; ++j) { acca[i][j] = zz; accb[i][j] = zz; }
  for (int k0 = 0; k0 < 1024; k0 += 32) {
    int tap = k0 >> 8;                       // block-uniform (256 % 32 == 0)
    int ic = (k0 & 255) + kh;
    __syncthreads();
    {  // A stage: 16 shorts/thread, zero for causal pad rows
      uint4 v0 = {0,0,0,0}, v1 = {0,0,0,0};
      if (al + tap >= 3) {
        const uint4* p = (const uint4*)(xin + (size_t)(arow + tap - 3)*D_ + ic);
        v0 = p[0]; v1 = p[1];
      }
      *(uint4*)&sA[lr*SSTR + kh]     = v0;
      *(uint4*)&sA[lr*SSTR + kh + 8] = v1;
    }
    {  // B stage
      const uint4* pa = (const uint4*)(wT + (size_t)(n0+lr)*1024 + k0 + kh);
      const uint4* pb = (const uint4*)(wT + (size_t)(256+n0+lr)*1024 + k0 + kh);
      *(uint4*)&sBa[lr*SSTR + kh]     = pa[0];
      *(uint4*)&sBa[lr*SSTR + kh + 8] = pa[1];
      *(uint4*)&sBb[lr*SSTR + kh]     = pb[0];
      *(uint4*)&sBb[lr*SSTR + kh + 8] = pb[1];
    }
    __syncthreads();
    s16x8 am[4], baf[4], bbf[4];
    #pragma unroll
    for (int i = 0; i < 4; ++i)
      am[i] = *(const s16x8*)&sA[(moff + i*16 + l15)*SSTR + koff];
    #pragma unroll
    for (int j = 0; j < 4; ++j) {
      baf[j] = *(const s16x8*)&sBa[(noff + j*16 + l15)*SSTR + koff];
      bbf[j] = *(const s16x8*)&sBb[(noff + j*16 + l15)*SSTR + koff];
    }
    #pragma unroll
    for (int i = 0; i < 4; ++i)
      #pragma unroll
      for (int j = 0; j < 4; ++j) {
        acca[i][j] = __builtin_amdgcn_mfma_f32_16x16x32_bf16(am[i], baf[j], acca[i][j], 0, 0, 0);
        accb[i][j] = __builtin_amdgcn_mfma_f32_16x16x32_bf16(am[i], bbf[j], accb[i][j], 0, 0, 0);
      }
  }
  #pragma unroll
  for (int j = 0; j < 4; ++j) {
    int col = n0 + noff + j*16 + l15;
    float ba = bias[col], bb = bias[col + 256];
    #pragma unroll
    for (int i = 0; i < 4; ++i) {
      int rbase = m0 + moff + i*16 + (lane >> 4)*4;
      #pragma unroll
      for (int r = 0; r < 4; ++r) {
        size_t off = (size_t)(rbase + r)*D_ + col;
        float za = acca[i][j][r] + ba;
        float zb = accb[i][j][r] + bb;
        float res = bf2f(xin[off]);
        xout[off] = f2bf(za * sigmoidf_(zb) + res);
      }
    }
  }
}

// ---------------- K5: predict = sigmoid(sum_d x*qe_next), x in bf16 --------
__global__ void k_pred(const unsigned short* __restrict__ x, const int* __restrict__ qs,
                       const float* __restrict__ Eq, float* __restrict__ out) {
  int lane = threadIdx.x & 63;
  int wv = threadIdx.x >> 6;
  int oi = blockIdx.x*4 + wv;
  int b = oi / 1023;
  int tp = oi - b*1023;
  int row = b*L_ + tp;
  int q = qs[row + 1];
  ushort4 u = ((const ushort4*)(x + (size_t)row*D_))[lane];
  float4 qv = ((const float4*)(Eq + (size_t)q*D_))[lane];
  float s = bf2f(u.x)*qv.x + bf2f(u.y)*qv.y + bf2f(u.z)*qv.z + bf2f(u.w)*qv.w;
  #pragma unroll
  for (int off = 32; off; off >>= 1) s += __shfl_xor(s, off);
  if (lane == 0) out[oi] = sigmoidf_(s);
}

extern "C" void kernel_launch(void* const* d_in, const int* in_sizes, int n_in,
                              void* d_out, int out_size, void* d_ws, size_t ws_size,
                              hipStream_t stream) {
  const int*   qs  = (const int*)d_in[0];
  const int*   cs  = (const int*)d_in[1];
  const float* cqc = (const float*)d_in[2];
  const float* Eq  = (const float*)d_in[3];
  const float* Ec  = (const float*)d_in[4];
  const float* W1w = (const float*)d_in[5];
  const float* W1b = (const float*)d_in[6];
  const float* W2w = (const float*)d_in[7];
  const float* W2b = (const float*)d_in[8];
  const float* cw  = (const float*)d_in[9];
  const float* cb  = (const float*)d_in[10];
  float* out = (float*)d_out;

  // Workspace layout (byte offsets), total 166 MB:
  //   [0,64M)    qe fp32          -> later conv ping-pong xB(0..32M), xC(32..64M)
  //   [64,128M)  attq fp32        -> later conv3 output xD (64..96M)
  //   [128M,..)  stv, s1v (0.5M)
  //   [129M,..)  W1bf, W2bf (1.25M), wT (3M)
  //   [134M,..)  xA bf16 (32M, mlp output / conv1 input)
  char* w8 = (char*)d_ws;
  float* qe   = (float*)w8;
  float* attq = (float*)(w8 + ((size_t)64 << 20));
  float* stv  = (float*)(w8 + ((size_t)128 << 20));
  float* s1v  = stv + M_;
  unsigned short* W1bf = (unsigned short*)(w8 + ((size_t)129 << 20));
  unsigned short* W2bf = W1bf + 256*1280;
  unsigned short* wT   = W2bf + 256*1280;          // 3 layers x 512x1024
  unsigned short* xA   = (unsigned short*)(w8 + ((size_t)134 << 20));
  unsigned short* xB   = (unsigned short*)w8;                          // 32 MB
  unsigned short* xC   = (unsigned short*)(w8 + ((size_t)32 << 20));   // 32 MB
  unsigned short* xD   = (unsigned short*)(w8 + ((size_t)64 << 20));   // 32 MB

  // weight conversions (independent of activations)
  k_cvt<<<(256*1280)/4/256, 256, 0, stream>>>(W1w, W1bf);
  k_cvt<<<(256*1280)/4/256, 256, 0, stream>>>(W2w, W2bf);
  k_cvt_convw<<<dim3(16, 8, 3), 256, 0, stream>>>(cw, wT);

  k_embed<<<(M_*D_/4)/256, 256, 0, stream>>>(qs, Eq, qe);
  k_attn <<<B_*(L_/TI), 256, 0, stream>>>(qe, cs, attq, stv, s1v);
  k_mlp_mfma<<<dim3(M_/128, 2), 256, 0, stream>>>(qe, attq, stv, s1v, cs, cqc, Ec,
                                                  W1bf, W1b, W2bf, W2b, xA);
  // conv ping-pong over recycled regions: xA -> xB -> xC -> xD
  k_conv_mfma<<<dim3(M_/128, 2), 256, 0, stream>>>(xA, wT,          cb,        xB);
  k_conv_mfma<<<dim3(M_/128, 2), 256, 0, stream>>>(xB, wT + 524288, cb + 512,  xC);
  k_conv_mfma<<<dim3(M_/128, 2), 256, 0, stream>>>(xC, wT + 1048576, cb + 1024, xD);
  k_pred <<<(B_*(L_-1))/4, 256, 0, stream>>>(xD, qs, Eq, out);
}

// Round 5
// 681.179 us; speedup vs baseline: 7.8895x; 2.9428x over previous
//
#include <hip/hip_runtime.h>
#include <hip/hip_bf16.h>

#define B_ 64
#define L_ 1024
#define D_ 256
#define M_ (B_*L_)

typedef __attribute__((ext_vector_type(8))) short s16x8;
typedef __attribute__((ext_vector_type(4))) float f32x4;

__device__ __forceinline__ float sigmoidf_(float z) { return 1.0f/(1.0f + __expf(-z)); }

__device__ __forceinline__ unsigned short f2bf(float x) {
  unsigned int u = __builtin_bit_cast(unsigned int, x);
  u += 0x7fffu + ((u >> 16) & 1u);          // RNE
  return (unsigned short)(u >> 16);
}
__device__ __forceinline__ float bf2f(unsigned short u) {
  unsigned int x = ((unsigned int)u) << 16;
  return __builtin_bit_cast(float, x);
}
__device__ __forceinline__ uint4 pack8(const float* f) {
  union { unsigned short u[8]; uint4 v; } r;
  #pragma unroll
  for (int i = 0; i < 8; ++i) r.u[i] = f2bf(f[i]);
  return r.v;
}

// ---------------- K1: gather+convert+transpose -----------------------------
// qe_bf[b*L+j][d] (bf16) and qeT[b][d][j] (bf16) from Eq[qs].
__global__ __launch_bounds__(256) void k_embedT(const int* __restrict__ qs,
    const float* __restrict__ Eq, unsigned short* __restrict__ qe_bf,
    unsigned short* __restrict__ qeT) {
  __shared__ unsigned short tile[64*264];
  int jc = blockIdx.x;       // 16 chunks of 64 rows
  int b  = blockIdx.y;
  int t = threadIdx.x;
  int jr = t >> 2, seg = (t & 3) * 64;
  size_t bL = (size_t)b * L_;
  int q = qs[bL + jc*64 + jr];
  {
    const float4* src = (const float4*)(Eq + (size_t)q*D_ + seg);
    float f[8];
    #pragma unroll
    for (int m = 0; m < 8; ++m) {
      float4 v0 = src[2*m], v1 = src[2*m+1];
      f[0]=v0.x; f[1]=v0.y; f[2]=v0.z; f[3]=v0.w;
      f[4]=v1.x; f[5]=v1.y; f[6]=v1.z; f[7]=v1.w;
      *(uint4*)&tile[jr*264 + seg + m*8] = pack8(f);
    }
  }
  __syncthreads();
  // out qe_bf (row-major copy)
  {
    unsigned short* dst = qe_bf + (bL + jc*64 + jr)*D_ + seg;
    #pragma unroll
    for (int m = 0; m < 8; ++m)
      *(uint4*)(dst + m*8) = *(const uint4*)&tile[jr*264 + seg + m*8];
  }
  // out qeT: thread t owns d = t, reads LDS column, writes contiguous row
  {
    int d = t;
    union { unsigned short u[64]; uint4 v[8]; } row;
    #pragma unroll
    for (int j = 0; j < 64; ++j) row.u[j] = tile[j*264 + d];
    unsigned short* dst = qeT + ((size_t)b*D_ + d)*L_ + jc*64;
    #pragma unroll
    for (int m = 0; m < 8; ++m) *(uint4*)(dst + m*8) = row.v[m];
  }
}

// ---------------- K2: MFMA fused causal attention --------------------------
// Per block: 64 Q-rows (i0..i0+63) of batch b; j-tiles of 32.
// S^T = K.Q^T via MFMA (A=sK[j][d], B=Q-frags in regs), exp+mask -> sP[i][j],
// O += P.V via MFMA (A=sP, B=sKT[d][j]). Zs/S1/Zd in regs, combined at end.
// denom = Zs + 1e-8*(Zs+Zdiag)  (exact reference algebra, validated R2).
#define KSTR 264
#define TSTR 40
#define PSTR 40

__global__ __launch_bounds__(256) void k_attn_mfma(
    const unsigned short* __restrict__ qe_bf, const unsigned short* __restrict__ qeT,
    const int* __restrict__ cs, unsigned short* __restrict__ attq,
    float* __restrict__ stv, float* __restrict__ s1v) {
  __shared__ unsigned short sK[32*KSTR];
  __shared__ unsigned short sKT[256*TSTR];
  __shared__ unsigned short sP[64*PSTR];
  __shared__ float scj[32];
  __shared__ float redz[64], reds1[64], redzd[64];
  // work-balanced tile order: CU gets pos {p,p+4,p+8,p+12} -> equal j-tile sums
  const int ord16[16] = {15,14,13,12, 8,9,10,11, 7,6,5,4, 0,1,2,3};
  int pos = blockIdx.x >> 6, b = blockIdx.x & 63;
  int t64 = ord16[pos];
  int i0 = t64 * 64;
  int t = threadIdx.x;
  int lane = t & 63, wv = t >> 6;
  int l15 = lane & 15, lq = lane >> 4;
  int koff = lq * 8;
  size_t bL = (size_t)b * L_;
  if (t < 64) { redz[t] = 0.f; reds1[t] = 0.f; redzd[t] = 0.f; }
  // QK partition (S^T: M=32 j, N=64 i): wave -> j-half mo, i-half no
  int mo = (wv & 1) * 16;
  int no = (wv >> 1) * 32;
  // persistent Q B-frags: qf[nt][ks] for i = i0+no+nt*16+l15
  s16x8 qf[2][8];
  #pragma unroll
  for (int nt = 0; nt < 2; ++nt) {
    const unsigned short* qrow = qe_bf + (bL + i0 + no + nt*16 + l15)*D_;
    #pragma unroll
    for (int ks = 0; ks < 8; ++ks)
      qf[nt][ks] = *(const s16x8*)(qrow + ks*32 + koff);
  }
  // PV partition (O: M=64 i, N=256 d): wave -> i-half mo2, d-half do_
  int mo2 = (wv & 1) * 32;
  int do_ = (wv >> 1) * 128;
  f32x4 oacc[2][8];
  f32x4 zz = {0.f, 0.f, 0.f, 0.f};
  #pragma unroll
  for (int i = 0; i < 2; ++i)
    #pragma unroll
    for (int j = 0; j < 8; ++j) oacc[i][j] = zz;
  float rzs[2] = {0.f, 0.f}, rs1[2] = {0.f, 0.f}, rzd[2] = {0.f, 0.f};
  int njt = 2*t64 + 2;
  for (int jt = 0; jt < njt; ++jt) {
    int j0 = jt * 32;
    __syncthreads();   // prev PV reads (and iter-0 init) complete
    {  // stage sK [32][256]: thread: row t>>3, 32-short segment (4 x uint4!)
      int jr = t >> 3, seg = (t & 7) * 32;
      const uint4* src = (const uint4*)(qe_bf + (bL + j0 + jr)*D_ + seg);
      #pragma unroll
      for (int m = 0; m < 4; ++m) *(uint4*)&sK[jr*KSTR + seg + m*8] = src[m];
    }
    {  // stage sKT [256][32]: thread: row d=t
      const uint4* src = (const uint4*)(qeT + ((size_t)b*D_ + t)*L_ + j0);
      #pragma unroll
      for (int m = 0; m < 4; ++m) *(uint4*)&sKT[t*TSTR + m*8] = src[m];
    }
    if (t < 32) scj[t] = (float)cs[bL + j0 + t];
    __syncthreads();
    // QK: S^T[j][i]
    f32x4 sacc[2]; sacc[0] = zz; sacc[1] = zz;
    #pragma unroll
    for (int ks = 0; ks < 8; ++ks) {
      s16x8 af = *(const s16x8*)&sK[(mo + l15)*KSTR + ks*32 + koff];
      sacc[0] = __builtin_amdgcn_mfma_f32_16x16x32_bf16(af, qf[0][ks], sacc[0], 0, 0, 0);
      sacc[1] = __builtin_amdgcn_mfma_f32_16x16x32_bf16(af, qf[1][ks], sacc[1], 0, 0, 0);
    }
    // exp + strict mask (C-layout: col=i=l15, row=j=lq*4+r), reduce, write sP
    #pragma unroll
    for (int nt = 0; nt < 2; ++nt) {
      int ig = i0 + no + nt*16 + l15;
      union { unsigned short u[4]; unsigned long long q; } pk;
      #pragma unroll
      for (int r = 0; r < 4; ++r) {
        int jloc = mo + lq*4 + r;
        int jg = j0 + jloc;
        float ex = __expf(sacc[nt][r]);
        float e = (jg < ig) ? ex : 0.f;
        rzs[nt] += e;
        rs1[nt] = fmaf(e, scj[jloc], rs1[nt]);
        if (jg == ig) rzd[nt] += ex;
        pk.u[r] = f2bf(e);
      }
      *(unsigned long long*)&sP[(no + nt*16 + l15)*PSTR + mo + lq*4] = pk.q;
    }
    __syncthreads();
    // PV: O[i][d] += P[i][j] * V[j][d]   (K=32 -> single MFMA k-step)
    s16x8 paf[2];
    #pragma unroll
    for (int mt = 0; mt < 2; ++mt)
      paf[mt] = *(const s16x8*)&sP[(mo2 + mt*16 + l15)*PSTR + koff];
    #pragma unroll
    for (int nt = 0; nt < 8; ++nt) {
      s16x8 bfr = *(const s16x8*)&sKT[(do_ + nt*16 + l15)*TSTR + koff];
      oacc[0][nt] = __builtin_amdgcn_mfma_f32_16x16x32_bf16(paf[0], bfr, oacc[0][nt], 0, 0, 0);
      oacc[1][nt] = __builtin_amdgcn_mfma_f32_16x16x32_bf16(paf[1], bfr, oacc[1][nt], 0, 0, 0);
    }
  }
  // cross-lane + cross-wave combine of Zs/S1/Zd
  #pragma unroll
  for (int nt = 0; nt < 2; ++nt) {
    float z = rzs[nt], s1 = rs1[nt], zd = rzd[nt];
    z  += __shfl_xor(z, 16);  z  += __shfl_xor(z, 32);
    s1 += __shfl_xor(s1, 16); s1 += __shfl_xor(s1, 32);
    zd += __shfl_xor(zd, 16); zd += __shfl_xor(zd, 32);
    if (lq == 0) {
      atomicAdd(&redz[no + nt*16 + l15], z);
      atomicAdd(&reds1[no + nt*16 + l15], s1);
      atomicAdd(&redzd[no + nt*16 + l15], zd);
    }
  }
  __syncthreads();
  if (t < 64) {
    float z = redz[t], zd = redzd[t], s1 = reds1[t];
    float inv = 1.0f / (z + 1e-8f*(z + zd));
    stv[bL + i0 + t] = z * inv;
    s1v[bL + i0 + t] = s1 * inv;
    redz[t] = inv;             // reuse as inv table
  }
  __syncthreads();
  #pragma unroll
  for (int mt = 0; mt < 2; ++mt)
    #pragma unroll
    for (int r = 0; r < 4; ++r) {
      int iloc = mo2 + mt*16 + lq*4 + r;
      float inv = redz[iloc];
      size_t base = (bL + i0 + iloc)*D_ + do_;
      #pragma unroll
      for (int nt = 0; nt < 8; ++nt)
        attq[base + nt*16 + l15] = f2bf(oacc[mt][nt][r] * inv);
    }
}

// ---------------- weight conversion: fp32 -> bf16 --------------------------
__global__ void k_cvt(const float* __restrict__ src, unsigned short* __restrict__ dst) {
  int i = blockIdx.x*256 + threadIdx.x;
  float4 v = ((const float4*)src)[i];
  union { unsigned short u[4]; uint2 q; } o;
  o.u[0] = f2bf(v.x); o.u[1] = f2bf(v.y); o.u[2] = f2bf(v.z); o.u[3] = f2bf(v.w);
  ((uint2*)dst)[i] = o.q;
}

// ------- conv weight transpose+convert: w[l][tap][ic][oc] -> wT[l][oc][tap*256+ic]
__global__ __launch_bounds__(256) void k_cvt_convw(const float* __restrict__ w,
                                                   unsigned short* __restrict__ wT) {
  __shared__ unsigned short lds[64*72];
  int l = blockIdx.z;
  int k0 = blockIdx.x * 64;
  int oc0 = blockIdx.y * 64;
  const float* src = w + (size_t)l*524288;
  unsigned short* dst = wT + (size_t)l*524288;
  int t = threadIdx.x;
  #pragma unroll
  for (int it = 0; it < 4; ++it) {
    int kr = it*16 + (t >> 4);
    int oc = (t & 15)*4;
    float4 v = *(const float4*)(src + (size_t)(k0+kr)*512 + oc0 + oc);
    lds[(oc+0)*72 + kr] = f2bf(v.x);
    lds[(oc+1)*72 + kr] = f2bf(v.y);
    lds[(oc+2)*72 + kr] = f2bf(v.z);
    lds[(oc+3)*72 + kr] = f2bf(v.w);
  }
  __syncthreads();
  #pragma unroll
  for (int it = 0; it < 2; ++it) {
    int ocr = it*32 + (t >> 3);
    int kx = (t & 7)*8;
    *(uint4*)(dst + (size_t)(oc0+ocr)*1024 + k0 + kx) = *(const uint4*)&lds[ocr*72 + kx];
  }
}

// ---------------- K3: MFMA fused double GEMM (MLP + GLU) -------------------
#define SSTR 40

__global__ __launch_bounds__(256, 2) void k_mlp_mfma(
    const unsigned short* __restrict__ qe_bf, const unsigned short* __restrict__ attq,
    const float* __restrict__ stv, const float* __restrict__ s1v,
    const int* __restrict__ cs, const float* __restrict__ cqc,
    const float* __restrict__ Ec,
    const unsigned short* __restrict__ W1bf, const float* __restrict__ W1b,
    const unsigned short* __restrict__ W2bf, const float* __restrict__ W2b,
    unsigned short* __restrict__ out) {
  __shared__ unsigned short sA[128*SSTR], sB1[128*SSTR], sB2[128*SSTR];
  int t = threadIdx.x;
  int m0 = blockIdx.x * 128;
  int n0 = blockIdx.y * 128;
  int lr = t >> 1, kh = (t & 1) * 16;
  int arow = m0 + lr;
  int lane = t & 63, wv = t >> 6;
  int moff = (wv & 1) * 64, noff = (wv >> 1) * 64;
  int l15 = lane & 15, koff = (lane >> 4) * 8;
  f32x4 acc1[4][4], acc2[4][4];
  f32x4 zz = {0.f, 0.f, 0.f, 0.f};
  #pragma unroll
  for (int i = 0; i < 4; ++i)
    #pragma unroll
    for (int j = 0; j < 4; ++j) { acc1[i][j] = zz; acc2[i][j] = zz; }
  for (int k0 = 0; k0 < 1280; k0 += 32) {
    __syncthreads();
    {  // A stage
      int seg = k0 >> 8;
      int ks = (k0 & 255) + kh;
      if (seg == 0 || seg == 2) {
        const uint4* p = (const uint4*)((seg == 0 ? qe_bf : attq) + (size_t)arow*D_ + ks);
        *(uint4*)&sA[lr*SSTR + kh]     = p[0];
        *(uint4*)&sA[lr*SSTR + kh + 8] = p[1];
      } else {
        float f[16];
        if (seg == 1) {
          int c = cs[arow];
          const float4* p = (const float4*)(Ec + (size_t)c*D_ + ks);
          #pragma unroll
          for (int m = 0; m < 4; ++m) { float4 v = p[m];
            f[4*m]=v.x; f[4*m+1]=v.y; f[4*m+2]=v.z; f[4*m+3]=v.w; }
        } else if (seg == 3) {
          float s1r = s1v[arow], s0r = stv[arow] - s1r;
          const float4* p1 = (const float4*)(Ec + D_ + ks);
          const float4* p0 = (const float4*)(Ec + ks);
          #pragma unroll
          for (int m = 0; m < 4; ++m) {
            float4 v1 = p1[m], v0 = p0[m];
            f[4*m]   = s1r*v1.x + s0r*v0.x;
            f[4*m+1] = s1r*v1.y + s0r*v0.y;
            f[4*m+2] = s1r*v1.z + s0r*v0.z;
            f[4*m+3] = s1r*v1.w + s0r*v0.w;
          }
        } else {
          const float4* p = (const float4*)(cqc + (size_t)arow*D_ + ks);
          #pragma unroll
          for (int m = 0; m < 4; ++m) { float4 v = p[m];
            f[4*m]=v.x; f[4*m+1]=v.y; f[4*m+2]=v.z; f[4*m+3]=v.w; }
        }
        *(uint4*)&sA[lr*SSTR + kh]     = pack8(f);
        *(uint4*)&sA[lr*SSTR + kh + 8] = pack8(f + 8);
      }
    }
    {  // B stage
      const uint4* p1 = (const uint4*)(W1bf + (size_t)(n0+lr)*1280 + k0 + kh);
      const uint4* p2 = (const uint4*)(W2bf + (size_t)(n0+lr)*1280 + k0 + kh);
      *(uint4*)&sB1[lr*SSTR + kh]     = p1[0];
      *(uint4*)&sB1[lr*SSTR + kh + 8] = p1[1];
      *(uint4*)&sB2[lr*SSTR + kh]     = p2[0];
      *(uint4*)&sB2[lr*SSTR + kh + 8] = p2[1];
    }
    __syncthreads();
    s16x8 am[4], b1f[4], b2f[4];
    #pragma unroll
    for (int i = 0; i < 4; ++i)
      am[i] = *(const s16x8*)&sA[(moff + i*16 + l15)*SSTR + koff];
    #pragma unroll
    for (int j = 0; j < 4; ++j) {
      b1f[j] = *(const s16x8*)&sB1[(noff + j*16 + l15)*SSTR + koff];
      b2f[j] = *(const s16x8*)&sB2[(noff + j*16 + l15)*SSTR + koff];
    }
    #pragma unroll
    for (int i = 0; i < 4; ++i)
      #pragma unroll
      for (int j = 0; j < 4; ++j) {
        acc1[i][j] = __builtin_amdgcn_mfma_f32_16x16x32_bf16(am[i], b1f[j], acc1[i][j], 0, 0, 0);
        acc2[i][j] = __builtin_amdgcn_mfma_f32_16x16x32_bf16(am[i], b2f[j], acc2[i][j], 0, 0, 0);
      }
  }
  #pragma unroll
  for (int j = 0; j < 4; ++j) {
    int col = n0 + noff + j*16 + l15;
    float b1 = W1b[col], b2 = W2b[col];
    #pragma unroll
    for (int i = 0; i < 4; ++i) {
      int rbase = m0 + moff + i*16 + (lane >> 4)*4;
      #pragma unroll
      for (int r = 0; r < 4; ++r) {
        float z1 = acc1[i][j][r] + b1;
        float z2 = acc2[i][j][r] + b2;
        out[(size_t)(rbase + r)*D_ + col] = f2bf(z1 * sigmoidf_(z2));
      }
    }
  }
}

// ---------------- K4: MFMA causal conv K=4 + GLU + residual ----------------
__global__ __launch_bounds__(256, 2) void k_conv_mfma(
    const unsigned short* __restrict__ xin, const unsigned short* __restrict__ wT,
    const float* __restrict__ bias, unsigned short* __restrict__ xout) {
  __shared__ unsigned short sA[128*SSTR], sBa[128*SSTR], sBb[128*SSTR];
  int t = threadIdx.x;
  int m0 = blockIdx.x * 128;
  int n0 = blockIdx.y * 128;
  int lr = t >> 1, kh = (t & 1) * 16;
  int arow = m0 + lr;
  int al = arow & (L_ - 1);
  int lane = t & 63, wv = t >> 6;
  int moff = (wv & 1) * 64, noff = (wv >> 1) * 64;
  int l15 = lane & 15, koff = (lane >> 4) * 8;
  f32x4 acca[4][4], accb[4][4];
  f32x4 zz = {0.f, 0.f, 0.f, 0.f};
  #pragma unroll
  for (int i = 0; i < 4; ++i)
    #pragma unroll
    for (int j = 0; j < 4; ++j) { acca[i][j] = zz; accb[i][j] = zz; }
  for (int k0 = 0; k0 < 1024; k0 += 32) {
    int tap = k0 >> 8;
    int ic = (k0 & 255) + kh;
    __syncthreads();
    {
      uint4 v0 = {0,0,0,0}, v1 = {0,0,0,0};
      if (al + tap >= 3) {
        const uint4* p = (const uint4*)(xin + (size_t)(arow + tap - 3)*D_ + ic);
        v0 = p[0]; v1 = p[1];
      }
      *(uint4*)&sA[lr*SSTR + kh]     = v0;
      *(uint4*)&sA[lr*SSTR + kh + 8] = v1;
    }
    {
      const uint4* pa = (const uint4*)(wT + (size_t)(n0+lr)*1024 + k0 + kh);
      const uint4* pb = (const uint4*)(wT + (size_t)(256+n0+lr)*1024 + k0 + kh);
      *(uint4*)&sBa[lr*SSTR + kh]     = pa[0];
      *(uint4*)&sBa[lr*SSTR + kh + 8] = pa[1];
      *(uint4*)&sBb[lr*SSTR + kh]     = pb[0];
      *(uint4*)&sBb[lr*SSTR + kh + 8] = pb[1];
    }
    __syncthreads();
    s16x8 am[4], baf[4], bbf[4];
    #pragma unroll
    for (int i = 0; i < 4; ++i)
      am[i] = *(const s16x8*)&sA[(moff + i*16 + l15)*SSTR + koff];
    #pragma unroll
    for (int j = 0; j < 4; ++j) {
      baf[j] = *(const s16x8*)&sBa[(noff + j*16 + l15)*SSTR + koff];
      bbf[j] = *(const s16x8*)&sBb[(noff + j*16 + l15)*SSTR + koff];
    }
    #pragma unroll
    for (int i = 0; i < 4; ++i)
      #pragma unroll
      for (int j = 0; j < 4; ++j) {
        acca[i][j] = __builtin_amdgcn_mfma_f32_16x16x32_bf16(am[i], baf[j], acca[i][j], 0, 0, 0);
        accb[i][j] = __builtin_amdgcn_mfma_f32_16x16x32_bf16(am[i], bbf[j], accb[i][j], 0, 0, 0);
      }
  }
  #pragma unroll
  for (int j = 0; j < 4; ++j) {
    int col = n0 + noff + j*16 + l15;
    float ba = bias[col], bb = bias[col + 256];
    #pragma unroll
    for (int i = 0; i < 4; ++i) {
      int rbase = m0 + moff + i*16 + (lane >> 4)*4;
      #pragma unroll
      for (int r = 0; r < 4; ++r) {
        size_t off = (size_t)(rbase + r)*D_ + col;
        float za = acca[i][j][r] + ba;
        float zb = accb[i][j][r] + bb;
        float res = bf2f(xin[off]);
        xout[off] = f2bf(za * sigmoidf_(zb) + res);
      }
    }
  }
}

// ---------------- K5: predict = sigmoid(sum_d x*Eq[qs_next]) ---------------
__global__ void k_pred(const unsigned short* __restrict__ x, const int* __restrict__ qs,
                       const float* __restrict__ Eq, float* __restrict__ out) {
  int lane = threadIdx.x & 63;
  int wv = threadIdx.x >> 6;
  int oi = blockIdx.x*4 + wv;
  int b = oi / 1023;
  int tp = oi - b*1023;
  int row = b*L_ + tp;
  int q = qs[row + 1];
  ushort4 u = ((const ushort4*)(x + (size_t)row*D_))[lane];
  float4 qv = ((const float4*)(Eq + (size_t)q*D_))[lane];
  float s = bf2f(u.x)*qv.x + bf2f(u.y)*qv.y + bf2f(u.z)*qv.z + bf2f(u.w)*qv.w;
  #pragma unroll
  for (int off = 32; off; off >>= 1) s += __shfl_xor(s, off);
  if (lane == 0) out[oi] = sigmoidf_(s);
}

extern "C" void kernel_launch(void* const* d_in, const int* in_sizes, int n_in,
                              void* d_out, int out_size, void* d_ws, size_t ws_size,
                              hipStream_t stream) {
  const int*   qs  = (const int*)d_in[0];
  const int*   cs  = (const int*)d_in[1];
  const float* cqc = (const float*)d_in[2];
  const float* Eq  = (const float*)d_in[3];
  const float* Ec  = (const float*)d_in[4];
  const float* W1w = (const float*)d_in[5];
  const float* W1b = (const float*)d_in[6];
  const float* W2w = (const float*)d_in[7];
  const float* W2b = (const float*)d_in[8];
  const float* cw  = (const float*)d_in[9];
  const float* cb  = (const float*)d_in[10];
  float* out = (float*)d_out;

  // Workspace (MiB offsets), ~133 MiB footprint with aliasing:
  //  [0,32)   qe_bf   (dead after mlp)  -> xC
  //  [32,64)  qeT     (dead after attn) -> xB
  //  [64,96)  attq    (dead after mlp)  -> xD
  //  [96,128) xA (mlp out / conv1 in)
  //  [128,..) stv, s1v, W1bf, W2bf, wT
  char* w8 = (char*)d_ws;
  unsigned short* qe_bf = (unsigned short*)w8;
  unsigned short* qeT   = (unsigned short*)(w8 + ((size_t)32 << 20));
  unsigned short* attq  = (unsigned short*)(w8 + ((size_t)64 << 20));
  unsigned short* xA    = (unsigned short*)(w8 + ((size_t)96 << 20));
  float* stv = (float*)(w8 + ((size_t)128 << 20));
  float* s1v = stv + M_;
  unsigned short* W1bf = (unsigned short*)(s1v + M_);
  unsigned short* W2bf = W1bf + 256*1280;
  unsigned short* wT   = W2bf + 256*1280;
  unsigned short* xB = qeT;
  unsigned short* xC = qe_bf;
  unsigned short* xD = attq;

  k_cvt<<<(256*1280)/4/256, 256, 0, stream>>>(W1w, W1bf);
  k_cvt<<<(256*1280)/4/256, 256, 0, stream>>>(W2w, W2bf);
  k_cvt_convw<<<dim3(16, 8, 3), 256, 0, stream>>>(cw, wT);

  k_embedT<<<dim3(16, 64), 256, 0, stream>>>(qs, Eq, qe_bf, qeT);
  k_attn_mfma<<<1024, 256, 0, stream>>>(qe_bf, qeT, cs, attq, stv, s1v);
  k_mlp_mfma<<<dim3(M_/128, 2), 256, 0, stream>>>(qe_bf, attq, stv, s1v, cs, cqc, Ec,
                                                  W1bf, W1b, W2bf, W2b, xA);
  k_conv_mfma<<<dim3(M_/128, 2), 256, 0, stream>>>(xA, wT,           cb,        xB);
  k_conv_mfma<<<dim3(M_/128, 2), 256, 0, stream>>>(xB, wT + 524288,  cb + 512,  xC);
  k_conv_mfma<<<dim3(M_/128, 2), 256, 0, stream>>>(xC, wT + 1048576, cb + 1024, xD);
  k_pred<<<(B_*(L_-1))/4, 256, 0, stream>>>(xD, qs, Eq, out);
}